// Round 12
// baseline (321.632 us; speedup 1.0000x reference)
//
#include <hip/hip_runtime.h>

// Problem constants: B=2, N=2048, C=512, H=8, HD=64
// Inputs fp32 (per reference); intermediates bf16 in ws; output fp32.
typedef __attribute__((ext_vector_type(8))) short bf16x8;
typedef __attribute__((ext_vector_type(4))) float f32x4;

__device__ __forceinline__ float bf2f(unsigned short u) {
  union { unsigned int i; float f; } c; c.i = ((unsigned int)u) << 16; return c.f;
}
__device__ __forceinline__ unsigned short f2bf(float x) {
  union { float f; unsigned int i; } c; c.f = x;
  return (unsigned short)((c.i + 0x7fffu + ((c.i >> 16) & 1u)) >> 16);
}
__device__ __forceinline__ bf16x8 as_bf(uint4 v) {
  union { uint4 u; bf16x8 b; } c; c.u = v; return c.b;
}

__device__ __forceinline__ uint4 ld8f(const float* p) {
  const float4 a = *(const float4*)p;
  const float4 b = *(const float4*)(p + 4);
  uint4 r;
  r.x = (unsigned)f2bf(a.x) | ((unsigned)f2bf(a.y) << 16);
  r.y = (unsigned)f2bf(a.z) | ((unsigned)f2bf(a.w) << 16);
  r.z = (unsigned)f2bf(b.x) | ((unsigned)f2bf(b.y) << 16);
  r.w = (unsigned)f2bf(b.z) | ((unsigned)f2bf(b.w) << 16);
  return r;
}

// fp32 -> bf16 pre-convert of x, pe, Wqkv, Wpos, Wproj (R11-proven).
__global__ __launch_bounds__(256) void k_cvt(const float* __restrict__ x,
    const float* __restrict__ pe, const float* __restrict__ wq,
    const float* __restrict__ wp, const float* __restrict__ wj,
    unsigned short* __restrict__ dst) {
  const long long i8 = ((long long)blockIdx.x * 256 + threadIdx.x) * 8;
  const float* src; long long off;
  if (i8 < 2097152)      { src = x;  off = i8; }
  else if (i8 < 4194304) { src = pe; off = i8 - 2097152; }
  else if (i8 < 4980736) { src = wq; off = i8 - 4194304; }
  else if (i8 < 5242880) { src = wp; off = i8 - 4980736; }
  else                   { src = wj; off = i8 - 5242880; }
  *(uint4*)&dst[i8] = ld8f(src + off);
}

// 64x64 output tile NT GEMM, bf16 in (R7 form — no prefetch rotation; at
// ~8 blocks/CU TLP hides staging latency).
template <int K>
__device__ __forceinline__ void gemm_mainloop(const unsigned short* __restrict__ Arow,
                                              const unsigned short* __restrict__ Wrow,
                                              short (*As)[72], short (*Ws)[72], f32x4 acc[4]) {
  const int tid = threadIdx.x;
  const int w = tid >> 6, lane = tid & 63, lm = lane & 15, lq = lane >> 4;
#pragma unroll
  for (int nt = 0; nt < 4; ++nt) acc[nt] = (f32x4){0.f, 0.f, 0.f, 0.f};
#pragma unroll 1
  for (int kc = 0; kc < K; kc += 64) {
    __syncthreads();
#pragma unroll
    for (int s = 0; s < 2; ++s) {
      int u = tid + s * 256, row = u >> 3, c8 = (u & 7) * 8;
      *(uint4*)&As[row][c8] = *(const uint4*)&Arow[(size_t)row * K + kc + c8];
      *(uint4*)&Ws[row][c8] = *(const uint4*)&Wrow[(size_t)row * K + kc + c8];
    }
    __syncthreads();
#pragma unroll
    for (int kk = 0; kk < 64; kk += 32) {
      bf16x8 a = *(const bf16x8*)&As[w * 16 + lm][kk + lq * 8];
#pragma unroll
      for (int nt = 0; nt < 4; ++nt) {
        bf16x8 bb = *(const bf16x8*)&Ws[nt * 16 + lm][kk + lq * 8];
        acc[nt] = __builtin_amdgcn_mfma_f32_16x16x32_bf16(a, bb, acc[nt], 0, 0, 0);
      }
    }
  }
}

// Fused: qkv = x @ Wqkv^T (cc0 < 1536) and pos = pe @ Wpos^T (cc0 >= 1536).
__global__ __launch_bounds__(256) void k_gemm_qkvpos(const unsigned short* __restrict__ xb,
    const unsigned short* __restrict__ peb, const unsigned short* __restrict__ wqb,
    const unsigned short* __restrict__ wpb, const float* __restrict__ ub,
    const float* __restrict__ vb, unsigned short* __restrict__ qu,
    unsigned short* __restrict__ qv, unsigned short* __restrict__ kg,
    unsigned short* __restrict__ vg, unsigned short* __restrict__ pos) {
  __shared__ short As[64][72], Ws[64][72];
  f32x4 acc[4];
  const int m0 = blockIdx.y * 64, cc0 = blockIdx.x * 64;
  const unsigned short* Arow = (cc0 < 1536 ? xb : peb) + (size_t)m0 * 512;
  const unsigned short* Wrow = (cc0 < 1536) ? (wqb + (size_t)cc0 * 512)
                                            : (wpb + (size_t)(cc0 - 1536) * 512);
  gemm_mainloop<512>(Arow, Wrow, As, Ws, acc);
  const int tid = threadIdx.x, w = tid >> 6, lane = tid & 63, lm = lane & 15, lq = lane >> 4;
#pragma unroll
  for (int nt = 0; nt < 4; ++nt) {
    const int cc = cc0 + nt * 16 + lm;
    const int sec = cc >> 9, rem = cc & 511, h = rem >> 6, d = rem & 63;
#pragma unroll
    for (int r = 0; r < 4; ++r) {
      const int m = m0 + w * 16 + lq * 4 + r;
      const int b = m >> 11, n = m & 2047;
      const size_t idx = ((size_t)(b * 8 + h) * 2048 + n) * 64 + d;
      const float val = acc[nt][r];
      if (sec == 0) {
        qu[idx] = f2bf(val + ub[rem]);
        qv[idx] = f2bf(val + vb[rem]);
      } else if (sec == 1) {
        kg[idx] = f2bf(val);
      } else if (sec == 2) {
        vg[idx] = f2bf(val);
      } else {
        pos[idx] = f2bf(val);
      }
    }
  }
}

// vt[b,h,d,n] = v[b,h,n,d]
__global__ __launch_bounds__(256) void k_transpose_v(const unsigned short* __restrict__ vg,
                                                     unsigned short* __restrict__ vt) {
  __shared__ short T[64][72];
  const int tid = threadIdx.x, bhid = blockIdx.y, n0 = blockIdx.x * 64;
#pragma unroll
  for (int s = 0; s < 2; ++s) {
    int u = tid + s * 256, row = u >> 3, c8 = (u & 7) * 8;
    *(uint4*)&T[row][c8] = *(const uint4*)&vg[((size_t)bhid * 2048 + n0 + row) * 64 + c8];
  }
  __syncthreads();
#pragma unroll
  for (int s = 0; s < 2; ++s) {
    int u = tid + s * 256, d = u >> 3, n8 = (u & 7) * 8;
    alignas(16) unsigned short tmp[8];
#pragma unroll
    for (int jj = 0; jj < 8; ++jj) tmp[jj] = (unsigned short)T[n8 + jj][d];
    *(uint4*)&vt[((size_t)bhid * 64 + d) * 2048 + n0 + n8] = *(const uint4*)tmp;
  }
}

// Fused flash attention R12: R11's band/softmax/Ps logic unchanged, but ALL
// K/V/pos B-frags are per-wave registers reloaded one full iteration ahead
// (pf after band MFMA, kf after QK^T, vf after P@V) — the R8 direct-global
// correctness with the R9/R11 rotation latency structure. LDS holds only
// Tl (stride 76) + Ps -> staging DS (~36 b128/wave/iter + 1.2e7 conflicts)
// is gone; barriers 3 -> 2.
__global__ __launch_bounds__(256, 2) void k_flash(const unsigned short* __restrict__ qu,
    const unsigned short* __restrict__ qv, const unsigned short* __restrict__ kg,
    const unsigned short* __restrict__ vt, const unsigned short* __restrict__ posg,
    unsigned short* __restrict__ og) {
  __shared__ short Tl[128 * 76];   // T[s][t], t in [0,65)
  __shared__ short Ps[4 * 16 * 72];
  const int tid = threadIdx.x, w = tid >> 6, lane = tid & 63, lm = lane & 15, lq = lane >> 4;
  const int bh = blockIdx.y, i0 = blockIdx.x * 64;
  const int iw = i0 + w * 16;
  const size_t bhs = (size_t)bh;
  const unsigned short* qub = qu + bhs * (2048 * 64);
  const unsigned short* qvb = qv + bhs * (2048 * 64);
  const unsigned short* kgb = kg + bhs * (2048 * 64);
  const unsigned short* vtb = vt + bhs * (64 * 2048);
  const unsigned short* pob = posg + bhs * (2048 * 64);
  // j-independent A-frags
  const bf16x8 au0 = *(const bf16x8*)&qub[(size_t)(iw + lm) * 64 + lq * 8];
  const bf16x8 au1 = *(const bf16x8*)&qub[(size_t)(iw + lm) * 64 + 32 + lq * 8];
  const bf16x8 av0 = *(const bf16x8*)&qvb[(size_t)(iw + lm) * 64 + lq * 8];
  const bf16x8 av1 = *(const bf16x8*)&qvb[(size_t)(iw + lm) * 64 + 32 + lq * 8];
  const int rowe = min(i0 + 49 + lm, 2047);  // t=64 row never read when i0==1984
  const bf16x8 ae0 = *(const bf16x8*)&qvb[(size_t)rowe * 64 + lq * 8];
  const bf16x8 ae1 = *(const bf16x8*)&qvb[(size_t)rowe * 64 + 32 + lq * 8];
  float lsum[4] = {0.f, 0.f, 0.f, 0.f};
  f32x4 oacc[4];
#pragma unroll
  for (int dt = 0; dt < 4; ++dt) oacc[dt] = (f32x4){0.f, 0.f, 0.f, 0.f};
  const int pb0 = 1983 - i0;
  // ---- pre-loop prefetch for jt=0 ----
  uint4 pf[12], kf[8], vf[8];
#pragma unroll
  for (int c = 0; c < 6; ++c) {
    const int ct = (c < 5) ? (3 - w + c) : w;
    const int prow = (pb0 + ct * 16 + lm) & 2047;
    pf[c * 2]     = *(const uint4*)&pob[(size_t)prow * 64 + lq * 8];
    pf[c * 2 + 1] = *(const uint4*)&pob[(size_t)prow * 64 + 32 + lq * 8];
  }
#pragma unroll
  for (int nt = 0; nt < 4; ++nt) {
    const size_t kro = (size_t)(nt * 16 + lm) * 64;
    kf[nt * 2]     = *(const uint4*)&kgb[kro + lq * 8];
    kf[nt * 2 + 1] = *(const uint4*)&kgb[kro + 32 + lq * 8];
  }
#pragma unroll
  for (int dt = 0; dt < 4; ++dt) {
    const size_t vro = (size_t)(dt * 16 + lm) * 2048;
    vf[dt * 2]     = *(const uint4*)&vtb[vro + lq * 8];
    vf[dt * 2 + 1] = *(const uint4*)&vtb[vro + 32 + lq * 8];
  }
#pragma unroll 1
  for (int jt = 0; jt < 32; ++jt) {
    const int j0 = jt * 64;
    __syncthreads();  // S1: prior iteration's Tl gathers complete
    // ---- band MFMA -> Tl transposed (b64-packed column writes) ----
#pragma unroll
    for (int c = 0; c < 5; ++c) {
      const int ct = 3 - w + c;
      f32x4 t0 = __builtin_amdgcn_mfma_f32_16x16x32_bf16(av0, as_bf(pf[c * 2]),
                                                         (f32x4){0.f,0.f,0.f,0.f}, 0, 0, 0);
      t0 = __builtin_amdgcn_mfma_f32_16x16x32_bf16(av1, as_bf(pf[c * 2 + 1]), t0, 0, 0, 0);
      alignas(8) unsigned short pk[4];
      pk[0] = f2bf(t0[0]); pk[1] = f2bf(t0[1]); pk[2] = f2bf(t0[2]); pk[3] = f2bf(t0[3]);
      *(uint2*)&Tl[(ct * 16 + lm) * 76 + w * 16 + lq * 4] = *(const uint2*)pk;
    }
    {  // extra strip: rows i0+49..i0+64, col-tile ct=w; keep only t=64 (C row 15)
      f32x4 e0 = __builtin_amdgcn_mfma_f32_16x16x32_bf16(ae0, as_bf(pf[10]),
                                                         (f32x4){0.f,0.f,0.f,0.f}, 0, 0, 0);
      e0 = __builtin_amdgcn_mfma_f32_16x16x32_bf16(ae1, as_bf(pf[11]), e0, 0, 0, 0);
      if (lq == 3) Tl[(w * 16 + lm) * 76 + 64] = (short)f2bf(e0[3]);
    }
    // ---- prefetch pos frags for jt+1 (full-iteration distance) ----
    if (jt < 31) {
      const int pbn = pb0 + j0 + 64;
#pragma unroll
      for (int c = 0; c < 6; ++c) {
        const int ct = (c < 5) ? (3 - w + c) : w;
        const int prow = (pbn + ct * 16 + lm) & 2047;
        pf[c * 2]     = *(const uint4*)&pob[(size_t)prow * 64 + lq * 8];
        pf[c * 2 + 1] = *(const uint4*)&pob[(size_t)prow * 64 + 32 + lq * 8];
      }
    }
    // ---- content QK^T from register K frags ----
    f32x4 cacc[4];
#pragma unroll
    for (int nt = 0; nt < 4; ++nt) {
      cacc[nt] = __builtin_amdgcn_mfma_f32_16x16x32_bf16(au0, as_bf(kf[nt * 2]),
                                                         (f32x4){0.f,0.f,0.f,0.f}, 0, 0, 0);
      cacc[nt] = __builtin_amdgcn_mfma_f32_16x16x32_bf16(au1, as_bf(kf[nt * 2 + 1]), cacc[nt], 0, 0, 0);
    }
    // ---- prefetch K frags for jt+1 ----
    if (jt < 31) {
      const int jn = j0 + 64;
#pragma unroll
      for (int nt = 0; nt < 4; ++nt) {
        const size_t kro = (size_t)(jn + nt * 16 + lm) * 64;
        kf[nt * 2]     = *(const uint4*)&kgb[kro + lq * 8];
        kf[nt * 2 + 1] = *(const uint4*)&kgb[kro + 32 + lq * 8];
      }
    }
    __syncthreads();  // S3: Tl visible
    // ---- gather shifted band scores ----
    float pvv[4][4];
    const int diag = i0 - j0;
    if (diag >= 64 || diag <= -128) {
      const int radd = (diag < 0) ? 1 : 0;  // all j<=i (0) or all j>=i+2 (1)
#pragma unroll
      for (int r = 0; r < 4; ++r) {
        const int rr = w * 16 + lq * 4 + r + radd;
        const int base = (64 + lm - rr) * 76 + rr;
#pragma unroll
        for (int nt = 0; nt < 4; ++nt)
          pvv[nt][r] = bf2f((unsigned short)Tl[base + nt * 1216]);
      }
    } else {  // 2 diagonal tiles: per-element shift logic
#pragma unroll
      for (int nt = 0; nt < 4; ++nt) {
        const int g = nt * 16 + lm;
#pragma unroll
        for (int r = 0; r < 4; ++r) {
          const int t = w * 16 + lq * 4 + r;
          const int d = g - t - diag;  // j - i
          float pv;
          if (d == 1) {
            pv = 0.f;
          } else {
            const int rr = t + ((d > 1) ? 1 : 0);
            pv = bf2f((unsigned short)Tl[(64 + g - rr) * 76 + rr]);
          }
          pvv[nt][r] = pv;
        }
      }
    }
    // ---- no-max softmax: p = exp2((c+pv)*0.125*log2e); partial sums only ----
#pragma unroll
    for (int nt = 0; nt < 4; ++nt) {
#pragma unroll
      for (int r = 0; r < 4; ++r) {
        const float p = exp2f((cacc[nt][r] + pvv[nt][r]) * 0.18033688f);
        lsum[r] += p;
        Ps[w * 1152 + (lq * 4 + r) * 72 + nt * 16 + lm] = (short)f2bf(p);
      }
    }
    // ---- P@V (per-wave LDS C->A transform; same-wave DS ordering) ----
    bf16x8 p0 = *(const bf16x8*)&Ps[w * 1152 + lm * 72 + lq * 8];
    bf16x8 p1 = *(const bf16x8*)&Ps[w * 1152 + lm * 72 + 32 + lq * 8];
#pragma unroll
    for (int dt = 0; dt < 4; ++dt) {
      oacc[dt] = __builtin_amdgcn_mfma_f32_16x16x32_bf16(p0, as_bf(vf[dt * 2]), oacc[dt], 0, 0, 0);
      oacc[dt] = __builtin_amdgcn_mfma_f32_16x16x32_bf16(p1, as_bf(vf[dt * 2 + 1]), oacc[dt], 0, 0, 0);
    }
    // ---- prefetch V frags for jt+1 (full-iteration distance) ----
    if (jt < 31) {
      const int jn = j0 + 64;
#pragma unroll
      for (int dt = 0; dt < 4; ++dt) {
        const size_t vro = (size_t)(dt * 16 + lm) * 2048 + jn;
        vf[dt * 2]     = *(const uint4*)&vtb[vro + lq * 8];
        vf[dt * 2 + 1] = *(const uint4*)&vtb[vro + 32 + lq * 8];
      }
    }
  }
  // ---- epilogue: one row-sum reduction, normalize, scatter ----
  const int b = bh >> 3, h = bh & 7;
#pragma unroll
  for (int r = 0; r < 4; ++r) {
    float l = lsum[r];
#pragma unroll
    for (int off = 1; off < 16; off <<= 1) l += __shfl_xor(l, off, 64);
    const float inv = 1.f / l;
    const int i = iw + lq * 4 + r;
#pragma unroll
    for (int dt = 0; dt < 4; ++dt)
      og[((size_t)b * 2048 + i) * 512 + h * 64 + dt * 16 + lm] = f2bf(oacc[dt][r] * inv);
  }
}

// out = O @ Wproj^T + bproj   (og/wproj bf16, bproj/out fp32)
__global__ __launch_bounds__(256) void k_gemm_proj(const unsigned short* __restrict__ og,
    const unsigned short* __restrict__ wjb, const float* __restrict__ bproj,
    float* __restrict__ out) {
  __shared__ short As[64][72], Ws[64][72];
  f32x4 acc[4];
  const int m0 = blockIdx.y * 64, cc0 = blockIdx.x * 64;
  gemm_mainloop<512>(og + (size_t)m0 * 512, wjb + (size_t)cc0 * 512, As, Ws, acc);
  const int tid = threadIdx.x, w = tid >> 6, lane = tid & 63, lm = lane & 15, lq = lane >> 4;
#pragma unroll
  for (int nt = 0; nt < 4; ++nt) {
    const int cc = cc0 + nt * 16 + lm;
    const float bias = bproj[cc];
#pragma unroll
    for (int r = 0; r < 4; ++r) {
      const int m = m0 + w * 16 + lq * 4 + r;
      out[(size_t)m * 512 + cc] = acc[nt][r] + bias;
    }
  }
}

extern "C" void kernel_launch(void* const* d_in, const int* in_sizes, int n_in,
                              void* d_out, int out_size, void* d_ws, size_t ws_size,
                              hipStream_t stream) {
  const float* x     = (const float*)d_in[0];
  const float* pe    = (const float*)d_in[1];
  const float* wqkv  = (const float*)d_in[2];
  const float* wpos  = (const float*)d_in[3];
  const float* ub    = (const float*)d_in[4];
  const float* vb    = (const float*)d_in[5];
  const float* wproj = (const float*)d_in[6];
  const float* bproj = (const float*)d_in[7];
  float* out = (float*)d_out;
  unsigned short* ws = (unsigned short*)d_ws;

  const size_t SZ = (size_t)2 * 8 * 2048 * 64;  // one [B,H,N,HD] buffer (2M elems)
  unsigned short* qu   = ws;
  unsigned short* qv   = qu + SZ;
  unsigned short* kg   = qv + SZ;
  unsigned short* vg   = kg + SZ;
  unsigned short* vt   = vg + SZ;
  unsigned short* pos  = vt + SZ;
  unsigned short* og   = pos + SZ;
  unsigned short* cvtb = og + SZ;  // bf16: x | pe | wqkv | wpos | wproj
  unsigned short* xb   = cvtb;
  unsigned short* peb  = cvtb + 2097152;
  unsigned short* wqb  = cvtb + 4194304;
  unsigned short* wpb  = cvtb + 4980736;
  unsigned short* wjb  = cvtb + 5242880;

  dim3 blk(256);
  hipLaunchKernelGGL(k_cvt,         dim3(2688),   blk, 0, stream, x, pe, wqkv, wpos, wproj, cvtb);
  hipLaunchKernelGGL(k_gemm_qkvpos, dim3(32, 64), blk, 0, stream,
                     xb, peb, wqb, wpb, ub, vb, qu, qv, kg, vg, pos);
  hipLaunchKernelGGL(k_transpose_v, dim3(32, 16), blk, 0, stream, vg, vt);
  hipLaunchKernelGGL(k_flash,       dim3(32, 16), blk, 0, stream, qu, qv, kg, vt, pos, og);
  hipLaunchKernelGGL(k_gemm_proj,   dim3(8, 64),  blk, 0, stream, og, wjb, bproj, out);
}

// Round 13
// 229.842 us; speedup vs baseline: 1.3994x; 1.3994x over previous
//
#include <hip/hip_runtime.h>

// Problem constants: B=2, N=2048, C=512, H=8, HD=64
// Inputs fp32 (per reference); intermediates bf16 in ws; output fp32.
typedef __attribute__((ext_vector_type(8))) short bf16x8;
typedef __attribute__((ext_vector_type(4))) float f32x4;

__device__ __forceinline__ float bf2f(unsigned short u) {
  union { unsigned int i; float f; } c; c.i = ((unsigned int)u) << 16; return c.f;
}
__device__ __forceinline__ unsigned short f2bf(float x) {
  union { float f; unsigned int i; } c; c.f = x;
  return (unsigned short)((c.i + 0x7fffu + ((c.i >> 16) & 1u)) >> 16);
}

__device__ __forceinline__ uint4 ld8f(const float* p) {
  const float4 a = *(const float4*)p;
  const float4 b = *(const float4*)(p + 4);
  uint4 r;
  r.x = (unsigned)f2bf(a.x) | ((unsigned)f2bf(a.y) << 16);
  r.y = (unsigned)f2bf(a.z) | ((unsigned)f2bf(a.w) << 16);
  r.z = (unsigned)f2bf(b.x) | ((unsigned)f2bf(b.y) << 16);
  r.w = (unsigned)f2bf(b.z) | ((unsigned)f2bf(b.w) << 16);
  return r;
}

// Async global->LDS, 16B per lane: HW writes lds_base + lane*16.
__device__ __forceinline__ void gload16(const unsigned short* g, short* l) {
  __builtin_amdgcn_global_load_lds((const __attribute__((address_space(1))) void*)g,
                                   (__attribute__((address_space(3))) void*)l, 16, 0, 0);
}

// fp32 -> bf16 pre-convert of x, pe, Wqkv, Wpos, Wproj (R11-proven).
__global__ __launch_bounds__(256) void k_cvt(const float* __restrict__ x,
    const float* __restrict__ pe, const float* __restrict__ wq,
    const float* __restrict__ wp, const float* __restrict__ wj,
    unsigned short* __restrict__ dst) {
  const long long i8 = ((long long)blockIdx.x * 256 + threadIdx.x) * 8;
  const float* src; long long off;
  if (i8 < 2097152)      { src = x;  off = i8; }
  else if (i8 < 4194304) { src = pe; off = i8 - 2097152; }
  else if (i8 < 4980736) { src = wq; off = i8 - 4194304; }
  else if (i8 < 5242880) { src = wp; off = i8 - 4980736; }
  else                   { src = wj; off = i8 - 5242880; }
  *(uint4*)&dst[i8] = ld8f(src + off);
}

// 128x128 NT GEMM mainloop (m97 ladder): 256 threads = 2x2 waves, each wave a
// 64x64 subtile (4x4 MFMA 16x16x32). Staging via global_load_lds width=16.
// LDS layout: row stride 64 shorts, XOR-swizzled chunks (physical chunk =
// logical ^ (row&7)) — achieved by permuting the per-lane GLOBAL source
// column, since the HW lane-scatter is fixed. Frag reads then tile all banks.
// K=512. A row-major [M,512] bf16, W row-major [Nc,512] bf16.
__device__ __forceinline__ void gemm128_mainloop(const unsigned short* __restrict__ Arow,
                                                 const unsigned short* __restrict__ Wrow,
                                                 short* Asl, short* Wsl, f32x4 acc[4][4]) {
  const int tid = threadIdx.x, w = tid >> 6, lane = tid & 63, lm = lane & 15, lq = lane >> 4;
  const int wm = w >> 1, wn = w & 1;
  const int lrow = lane >> 3;                       // 0..7 within an 8-row slab
  const int gcol = (((lane & 7) ^ lrow) * 8);       // swizzled source chunk
#pragma unroll
  for (int mt = 0; mt < 4; ++mt)
#pragma unroll
    for (int nt = 0; nt < 4; ++nt) acc[mt][nt] = (f32x4){0.f, 0.f, 0.f, 0.f};
#pragma unroll 1
  for (int kc = 0; kc < 512; kc += 64) {
    __syncthreads();  // prior iteration's frag reads done
#pragma unroll
    for (int ld = 0; ld < 4; ++ld) {
      const int rbase = w * 32 + ld * 8;
      gload16(&Arow[(size_t)(rbase + lrow) * 512 + kc + gcol], &Asl[rbase * 64]);
      gload16(&Wrow[(size_t)(rbase + lrow) * 512 + kc + gcol], &Wsl[rbase * 64]);
    }
    __syncthreads();  // staging visible (vmcnt drained by barrier)
#pragma unroll
    for (int kk = 0; kk < 2; ++kk) {
      const int pcs = ((kk * 4 + lq) ^ (lm & 7)) * 8;
      bf16x8 af[4], bf[4];
#pragma unroll
      for (int mt = 0; mt < 4; ++mt)
        af[mt] = *(const bf16x8*)&Asl[(wm * 64 + mt * 16 + lm) * 64 + pcs];
#pragma unroll
      for (int nt = 0; nt < 4; ++nt)
        bf[nt] = *(const bf16x8*)&Wsl[(wn * 64 + nt * 16 + lm) * 64 + pcs];
#pragma unroll
      for (int mt = 0; mt < 4; ++mt)
#pragma unroll
        for (int nt = 0; nt < 4; ++nt)
          acc[mt][nt] = __builtin_amdgcn_mfma_f32_16x16x32_bf16(af[mt], bf[nt], acc[mt][nt], 0, 0, 0);
    }
  }
}

// Fused 128-tile: qkv = x @ Wqkv^T (cc0 < 1536) and pos = pe @ Wpos^T.
// sec 0 -> qu/qv (+u/v bias), 1 -> k, 2 -> v, 3 -> pos.
__global__ __launch_bounds__(256) void k_gemm_qkvpos(const unsigned short* __restrict__ xb,
    const unsigned short* __restrict__ peb, const unsigned short* __restrict__ wqb,
    const unsigned short* __restrict__ wpb, const float* __restrict__ ub,
    const float* __restrict__ vb, unsigned short* __restrict__ qu,
    unsigned short* __restrict__ qv, unsigned short* __restrict__ kg,
    unsigned short* __restrict__ vg, unsigned short* __restrict__ pos) {
  __shared__ short Asl[128 * 64], Wsl[128 * 64];
  f32x4 acc[4][4];
  const int m0 = blockIdx.y * 128, cc0 = blockIdx.x * 128;
  const unsigned short* Arow = (cc0 < 1536 ? xb : peb) + (size_t)m0 * 512;
  const unsigned short* Wrow = (cc0 < 1536) ? (wqb + (size_t)cc0 * 512)
                                            : (wpb + (size_t)(cc0 - 1536) * 512);
  gemm128_mainloop(Arow, Wrow, Asl, Wsl, acc);
  const int tid = threadIdx.x, w = tid >> 6, lane = tid & 63, lm = lane & 15, lq = lane >> 4;
  const int wm = w >> 1, wn = w & 1;
#pragma unroll
  for (int nt = 0; nt < 4; ++nt) {
    const int cc = cc0 + wn * 64 + nt * 16 + lm;
    const int sec = cc >> 9, rem = cc & 511, h = rem >> 6, d = rem & 63;
#pragma unroll
    for (int mt = 0; mt < 4; ++mt) {
#pragma unroll
      for (int r = 0; r < 4; ++r) {
        const int m = m0 + wm * 64 + mt * 16 + lq * 4 + r;
        const int b = m >> 11, n = m & 2047;
        const size_t idx = ((size_t)(b * 8 + h) * 2048 + n) * 64 + d;
        const float val = acc[mt][nt][r];
        if (sec == 0) {
          qu[idx] = f2bf(val + ub[rem]);
          qv[idx] = f2bf(val + vb[rem]);
        } else if (sec == 1) {
          kg[idx] = f2bf(val);
        } else if (sec == 2) {
          vg[idx] = f2bf(val);
        } else {
          pos[idx] = f2bf(val);
        }
      }
    }
  }
}

// vt[b,h,d,n] = v[b,h,n,d]
__global__ __launch_bounds__(256) void k_transpose_v(const unsigned short* __restrict__ vg,
                                                     unsigned short* __restrict__ vt) {
  __shared__ short T[64][72];
  const int tid = threadIdx.x, bhid = blockIdx.y, n0 = blockIdx.x * 64;
#pragma unroll
  for (int s = 0; s < 2; ++s) {
    int u = tid + s * 256, row = u >> 3, c8 = (u & 7) * 8;
    *(uint4*)&T[row][c8] = *(const uint4*)&vg[((size_t)bhid * 2048 + n0 + row) * 64 + c8];
  }
  __syncthreads();
#pragma unroll
  for (int s = 0; s < 2; ++s) {
    int u = tid + s * 256, d = u >> 3, n8 = (u & 7) * 8;
    alignas(16) unsigned short tmp[8];
#pragma unroll
    for (int jj = 0; jj < 8; ++jj) tmp[jj] = (unsigned short)T[n8 + jj][d];
    *(uint4*)&vt[((size_t)bhid * 64 + d) * 2048 + n0 + n8] = *(const uint4*)tmp;
  }
}

// Fused flash attention — byte-for-byte the R11 k_flash (fastest measured,
// 124.4us): coop LDS staging + reg-held next-tile prefetch, no-max softmax,
// transposed Tl [s][t] stride 76, Ps aliasing Ks. (R12's direct-global frags
// dropped conflicts to 2.6e6 but shattered coalescing -> 211us; staged wins.)
__global__ __launch_bounds__(256) void k_flash(const unsigned short* __restrict__ qu,
    const unsigned short* __restrict__ qv, const unsigned short* __restrict__ kg,
    const unsigned short* __restrict__ vt, const unsigned short* __restrict__ posg,
    unsigned short* __restrict__ og) {
  __shared__ short SB[28160];
  short* Ks = SB;            // 64 x stride 72 (aliased by Ps after S3)
  short* Vs = SB + 4608;     // 64 x stride 72
  short* Pn = SB + 9216;     // 128 x stride 72, circular pos window
  short* Tl = SB + 18432;    // T[s][t]: 128 x stride 76, t in [0,65)
  short* Ps = SB;            // alias of Ks
  const int tid = threadIdx.x, w = tid >> 6, lane = tid & 63, lm = lane & 15, lq = lane >> 4;
  const int bh = blockIdx.y, i0 = blockIdx.x * 64;
  const int iw = i0 + w * 16;
  const size_t bhs = (size_t)bh;
  const unsigned short* qub = qu + bhs * (2048 * 64);
  const unsigned short* qvb = qv + bhs * (2048 * 64);
  const unsigned short* pob = posg + bhs * (2048 * 64);
  const bf16x8 au0 = *(const bf16x8*)&qub[(size_t)(iw + lm) * 64 + lq * 8];
  const bf16x8 au1 = *(const bf16x8*)&qub[(size_t)(iw + lm) * 64 + 32 + lq * 8];
  const bf16x8 av0 = *(const bf16x8*)&qvb[(size_t)(iw + lm) * 64 + lq * 8];
  const bf16x8 av1 = *(const bf16x8*)&qvb[(size_t)(iw + lm) * 64 + 32 + lq * 8];
  const int rowe = min(i0 + 49 + lm, 2047);  // t=64 row never read when i0==1984
  const bf16x8 ae0 = *(const bf16x8*)&qvb[(size_t)rowe * 64 + lq * 8];
  const bf16x8 ae1 = *(const bf16x8*)&qvb[(size_t)rowe * 64 + 32 + lq * 8];
  float lsum[4] = {0.f, 0.f, 0.f, 0.f};
  f32x4 oacc[4];
#pragma unroll
  for (int dt = 0; dt < 4; ++dt) oacc[dt] = (f32x4){0.f, 0.f, 0.f, 0.f};
  const int krow = tid >> 3, kc8 = (tid & 7) * 8;
  const int pb0 = 1983 - i0;
  uint4 kr0 = *(const uint4*)&kg[(bhs * 2048 + krow) * 64 + kc8];
  uint4 kr1 = *(const uint4*)&kg[(bhs * 2048 + krow + 32) * 64 + kc8];
  uint4 vr0 = *(const uint4*)&vt[(bhs * 64 + krow) * 2048 + kc8];
  uint4 vr1 = *(const uint4*)&vt[(bhs * 64 + krow + 32) * 2048 + kc8];
  uint4 pr[4];
#pragma unroll
  for (int s = 0; s < 4; ++s) {
    int u = tid + s * 256, prow = u >> 3, c8 = (u & 7) * 8;
    int grow = (pb0 + prow + 4096) & 2047;
    pr[s] = *(const uint4*)&pob[(size_t)grow * 64 + c8];
  }
#pragma unroll 1
  for (int jt = 0; jt < 32; ++jt) {
    const int j0 = jt * 64;
    const int pb = pb0 + j0;
    __syncthreads();  // S1: prior iteration's LDS reads done
    *(uint4*)&Ks[krow * 72 + kc8] = kr0;
    *(uint4*)&Ks[(krow + 32) * 72 + kc8] = kr1;
    *(uint4*)&Vs[krow * 72 + kc8] = vr0;
    *(uint4*)&Vs[(krow + 32) * 72 + kc8] = vr1;
    if (jt == 0) {
#pragma unroll
      for (int s = 0; s < 4; ++s) {
        int u = tid + s * 256, prow = u >> 3, c8 = (u & 7) * 8;
        int slot = (pb + prow) & 127;
        *(uint4*)&Pn[slot * 72 + c8] = pr[s];
      }
    } else {
#pragma unroll
      for (int s = 0; s < 2; ++s) {
        int u = tid + s * 256, prow = u >> 3, c8 = (u & 7) * 8;
        int slot = (pb + 64 + prow) & 127;
        *(uint4*)&Pn[slot * 72 + c8] = pr[s];
      }
    }
    __syncthreads();  // S2: staging visible
    if (jt < 31) {
      const int jn = j0 + 64;
      kr0 = *(const uint4*)&kg[(bhs * 2048 + jn + krow) * 64 + kc8];
      kr1 = *(const uint4*)&kg[(bhs * 2048 + jn + krow + 32) * 64 + kc8];
      vr0 = *(const uint4*)&vt[(bhs * 64 + krow) * 2048 + jn + kc8];
      vr1 = *(const uint4*)&vt[(bhs * 64 + krow + 32) * 2048 + jn + kc8];
#pragma unroll
      for (int s = 0; s < 2; ++s) {
        int u = tid + s * 256, prow = u >> 3, c8 = (u & 7) * 8;
        int grow = (pb + 128 + prow + 4096) & 2047;
        pr[s] = *(const uint4*)&pob[(size_t)grow * 64 + c8];
      }
    }
    const int pbm = pb & 127;
#pragma unroll
    for (int c = 0; c < 5; ++c) {
      const int ct = 3 - w + c;
      const int prow = (pbm + ct * 16 + lm) & 127;
      bf16x8 b0 = *(const bf16x8*)&Pn[prow * 72 + lq * 8];
      bf16x8 b1 = *(const bf16x8*)&Pn[prow * 72 + 32 + lq * 8];
      f32x4 t0 = __builtin_amdgcn_mfma_f32_16x16x32_bf16(av0, b0, (f32x4){0.f,0.f,0.f,0.f}, 0, 0, 0);
      t0 = __builtin_amdgcn_mfma_f32_16x16x32_bf16(av1, b1, t0, 0, 0, 0);
      alignas(8) unsigned short pk[4];
      pk[0] = f2bf(t0[0]); pk[1] = f2bf(t0[1]); pk[2] = f2bf(t0[2]); pk[3] = f2bf(t0[3]);
      *(uint2*)&Tl[(ct * 16 + lm) * 76 + w * 16 + lq * 4] = *(const uint2*)pk;
    }
    {
      const int prow = (pbm + w * 16 + lm) & 127;
      bf16x8 b0 = *(const bf16x8*)&Pn[prow * 72 + lq * 8];
      bf16x8 b1 = *(const bf16x8*)&Pn[prow * 72 + 32 + lq * 8];
      f32x4 e0 = __builtin_amdgcn_mfma_f32_16x16x32_bf16(ae0, b0, (f32x4){0.f,0.f,0.f,0.f}, 0, 0, 0);
      e0 = __builtin_amdgcn_mfma_f32_16x16x32_bf16(ae1, b1, e0, 0, 0, 0);
      if (lq == 3) Tl[(w * 16 + lm) * 76 + 64] = (short)f2bf(e0[3]);
    }
    f32x4 cacc[4];
#pragma unroll
    for (int nt = 0; nt < 4; ++nt) {
      bf16x8 b0 = *(const bf16x8*)&Ks[(nt * 16 + lm) * 72 + lq * 8];
      bf16x8 b1 = *(const bf16x8*)&Ks[(nt * 16 + lm) * 72 + 32 + lq * 8];
      cacc[nt] = __builtin_amdgcn_mfma_f32_16x16x32_bf16(au0, b0, (f32x4){0.f,0.f,0.f,0.f}, 0, 0, 0);
      cacc[nt] = __builtin_amdgcn_mfma_f32_16x16x32_bf16(au1, b1, cacc[nt], 0, 0, 0);
    }
    __syncthreads();  // S3: Tl visible; Ks reads done -> Ps alias safe
    float pvv[4][4];
    const int diag = i0 - j0;
    if (diag >= 64 || diag <= -128) {
      const int radd = (diag < 0) ? 1 : 0;
#pragma unroll
      for (int r = 0; r < 4; ++r) {
        const int rr = w * 16 + lq * 4 + r + radd;
        const int base = (64 + lm - rr) * 76 + rr;
#pragma unroll
        for (int nt = 0; nt < 4; ++nt)
          pvv[nt][r] = bf2f((unsigned short)Tl[base + nt * 1216]);
      }
    } else {
#pragma unroll
      for (int nt = 0; nt < 4; ++nt) {
        const int g = nt * 16 + lm;
#pragma unroll
        for (int r = 0; r < 4; ++r) {
          const int t = w * 16 + lq * 4 + r;
          const int d = g - t - diag;  // j - i
          float pv;
          if (d == 1) {
            pv = 0.f;
          } else {
            const int rr = t + ((d > 1) ? 1 : 0);
            pv = bf2f((unsigned short)Tl[(64 + g - rr) * 76 + rr]);
          }
          pvv[nt][r] = pv;
        }
      }
    }
#pragma unroll
    for (int nt = 0; nt < 4; ++nt) {
#pragma unroll
      for (int r = 0; r < 4; ++r) {
        const float p = exp2f((cacc[nt][r] + pvv[nt][r]) * 0.18033688f);
        lsum[r] += p;
        Ps[w * 1152 + (lq * 4 + r) * 72 + nt * 16 + lm] = (short)f2bf(p);
      }
    }
    bf16x8 p0 = *(const bf16x8*)&Ps[w * 1152 + lm * 72 + lq * 8];
    bf16x8 p1 = *(const bf16x8*)&Ps[w * 1152 + lm * 72 + 32 + lq * 8];
#pragma unroll
    for (int dt = 0; dt < 4; ++dt) {
      bf16x8 v0 = *(const bf16x8*)&Vs[(dt * 16 + lm) * 72 + lq * 8];
      bf16x8 v1 = *(const bf16x8*)&Vs[(dt * 16 + lm) * 72 + 32 + lq * 8];
      oacc[dt] = __builtin_amdgcn_mfma_f32_16x16x32_bf16(p0, v0, oacc[dt], 0, 0, 0);
      oacc[dt] = __builtin_amdgcn_mfma_f32_16x16x32_bf16(p1, v1, oacc[dt], 0, 0, 0);
    }
  }
  const int b = bh >> 3, h = bh & 7;
#pragma unroll
  for (int r = 0; r < 4; ++r) {
    float l = lsum[r];
#pragma unroll
    for (int off = 1; off < 16; off <<= 1) l += __shfl_xor(l, off, 64);
    const float inv = 1.f / l;
    const int i = iw + lq * 4 + r;
#pragma unroll
    for (int dt = 0; dt < 4; ++dt)
      og[((size_t)b * 2048 + i) * 512 + h * 64 + dt * 16 + lm] = f2bf(oacc[dt][r] * inv);
  }
}

// out = O @ Wproj^T + bproj, 128-tile (og/wproj bf16, bproj/out fp32)
__global__ __launch_bounds__(256) void k_gemm_proj(const unsigned short* __restrict__ og,
    const unsigned short* __restrict__ wjb, const float* __restrict__ bproj,
    float* __restrict__ out) {
  __shared__ short Asl[128 * 64], Wsl[128 * 64];
  f32x4 acc[4][4];
  const int m0 = blockIdx.y * 128, cc0 = blockIdx.x * 128;
  gemm128_mainloop(og + (size_t)m0 * 512, wjb + (size_t)cc0 * 512, Asl, Wsl, acc);
  const int tid = threadIdx.x, w = tid >> 6, lane = tid & 63, lm = lane & 15, lq = lane >> 4;
  const int wm = w >> 1, wn = w & 1;
#pragma unroll
  for (int nt = 0; nt < 4; ++nt) {
    const int cc = cc0 + wn * 64 + nt * 16 + lm;
    const float bias = bproj[cc];
#pragma unroll
    for (int mt = 0; mt < 4; ++mt) {
#pragma unroll
      for (int r = 0; r < 4; ++r) {
        const int m = m0 + wm * 64 + mt * 16 + lq * 4 + r;
        out[(size_t)m * 512 + cc] = acc[mt][nt][r] + bias;
      }
    }
  }
}

extern "C" void kernel_launch(void* const* d_in, const int* in_sizes, int n_in,
                              void* d_out, int out_size, void* d_ws, size_t ws_size,
                              hipStream_t stream) {
  const float* x     = (const float*)d_in[0];
  const float* pe    = (const float*)d_in[1];
  const float* wqkv  = (const float*)d_in[2];
  const float* wpos  = (const float*)d_in[3];
  const float* ub    = (const float*)d_in[4];
  const float* vb    = (const float*)d_in[5];
  const float* wproj = (const float*)d_in[6];
  const float* bproj = (const float*)d_in[7];
  float* out = (float*)d_out;
  unsigned short* ws = (unsigned short*)d_ws;

  const size_t SZ = (size_t)2 * 8 * 2048 * 64;  // one [B,H,N,HD] buffer (2M elems)
  unsigned short* qu   = ws;
  unsigned short* qv   = qu + SZ;
  unsigned short* kg   = qv + SZ;
  unsigned short* vg   = kg + SZ;
  unsigned short* vt   = vg + SZ;
  unsigned short* pos  = vt + SZ;
  unsigned short* og   = pos + SZ;
  unsigned short* cvtb = og + SZ;  // bf16: x | pe | wqkv | wpos | wproj
  unsigned short* xb   = cvtb;
  unsigned short* peb  = cvtb + 2097152;
  unsigned short* wqb  = cvtb + 4194304;
  unsigned short* wpb  = cvtb + 4980736;
  unsigned short* wjb  = cvtb + 5242880;

  dim3 blk(256);
  hipLaunchKernelGGL(k_cvt,         dim3(2688),   blk, 0, stream, x, pe, wqkv, wpos, wproj, cvtb);
  hipLaunchKernelGGL(k_gemm_qkvpos, dim3(16, 32), blk, 0, stream,
                     xb, peb, wqb, wpb, ub, vb, qu, qv, kg, vg, pos);
  hipLaunchKernelGGL(k_transpose_v, dim3(32, 16), blk, 0, stream, vg, vt);
  hipLaunchKernelGGL(k_flash,       dim3(32, 16), blk, 0, stream, qu, qv, kg, vt, pos, og);
  hipLaunchKernelGGL(k_gemm_proj,   dim3(4, 32),  blk, 0, stream, og, wjb, bproj, out);
}